// Round 9
// baseline (338.979 us; speedup 1.0000x reference)
//
#include <hip/hip_runtime.h>
#include <math.h>

// GCN forward, CSR-gather; bf16 xs/W2/ht1; block-aggregated pooling.
// CSR build = two-level bucket sort (append-order writes only).
// Requires N <= 65536 (src packed in 16 bits) -- holds for N=50000.
// Pipeline (7 dispatches):
//   k_bhist   : per-block 196-bin histogram -> private global slices
//               (no memset, no global atomics)
//   k_mid     : 1 block: reduce+scan bucket counts -> bstart/bcur;
//               gptr = lower_bound(batch,g); gsum = 0; rowptr[N] = E;
//               W2bf = bf16(W2)
//   k_bfill   : per-block LDS hist + reservation; append (dstLocal<<16|src)
//   k_bsort   : block/bucket: LDS 256-bin sort -> rowptr, dinv, sorted col;
//               + xsb = bf16(x*dinv) for its own 256 nodes
//   k_l12g    : FUSED: 8 waves gather rank-16 neighborhoods -> arow LDS;
//               h1 = relu(dinv*(arow@W1)+b1); ht1b = bf16((h1@W2bf)*dinv)
//   k_gat128pool : wave/node gather, 4-node LDS merge -> ~1 atomic set/block
//   k_head    : pooled = gsum/cnt; label/domain heads

#define BCAP 24576   // max edges per 256-node bucket (mean ~8.2K; 3x headroom)

__device__ __forceinline__ float4 bf4(uint2 u) {
    return make_float4(__uint_as_float(u.x << 16),
                       __uint_as_float(u.x & 0xffff0000u),
                       __uint_as_float(u.y << 16),
                       __uint_as_float(u.y & 0xffff0000u));
}

__device__ __forceinline__ void bf4acc(uint2 u, float* a) {
    a[0] += __uint_as_float(u.x << 16);
    a[1] += __uint_as_float(u.x & 0xffff0000u);
    a[2] += __uint_as_float(u.y << 16);
    a[3] += __uint_as_float(u.y & 0xffff0000u);
}

__device__ __forceinline__ unsigned pack2(float a, float b) {   // RNE bf16 pair
    unsigned ua = __float_as_uint(a), ub = __float_as_uint(b);
    ua = (ua + 0x7fffu + ((ua >> 16) & 1u)) >> 16;
    ub = (ub + 0x7fffu + ((ub >> 16) & 1u)) >> 16;
    return ua | (ub << 16);
}

// ---- CSR build, phase 1: bucket histogram into per-block slices ----
__global__ __launch_bounds__(256) void k_bhist(const int* __restrict__ ei,
                                               int* __restrict__ bcnt2,
                                               int E, int chunk, int NB) {
    __shared__ int bins[256];
    for (int t = threadIdx.x; t < NB; t += 256) bins[t] = 0;
    __syncthreads();
    const int e0 = blockIdx.x * chunk;
    int e1 = e0 + chunk; if (e1 > E) e1 = E;
    for (int j = e0 + (int)threadIdx.x; j < e1; j += 256)
        atomicAdd(&bins[ei[E + j] >> 8], 1);
    __syncthreads();
    for (int t = threadIdx.x; t < NB; t += 256)
        bcnt2[blockIdx.x * NB + t] = bins[t];
}

// ---- phase 2 (1 block): reduce+scan; gptr; gsum=0; rowptr[N]; W2 pack ----
__global__ __launch_bounds__(256) void k_mid(
        const int* __restrict__ bcnt2, int* __restrict__ bstart,
        int* __restrict__ bcur, const int* __restrict__ batch,
        int* __restrict__ gptr, float* __restrict__ gsum,
        int* __restrict__ rowptr, const float* __restrict__ W2,
        unsigned short* __restrict__ W2bf,
        int NB, int FB, int E, int N, int G) {
    __shared__ int s[256];
    const int t = threadIdx.x;
    int v = 0;
    if (t < NB)
        for (int b = 0; b < FB; ++b) v += bcnt2[b * NB + t];
    s[t] = v;
    __syncthreads();
    for (int off = 1; off < 256; off <<= 1) {
        int add = (t >= off) ? s[t - off] : 0;
        __syncthreads();
        s[t] += add;
        __syncthreads();
    }
    if (t < NB) { bstart[t] = s[t] - v; bcur[t] = s[t] - v; }
    if (t == 0) { bstart[NB] = E; rowptr[N] = E; }
    // gsum zero (G*128 floats)
    for (int i = t; i < G * 32; i += 256)
        ((float4*)gsum)[i] = make_float4(0.f, 0.f, 0.f, 0.f);
    // gptr via binary search on sorted batch
    for (int g = t; g <= G; g += 256) {
        int lo = 0, hi = N;
        while (lo < hi) {
            int mid = (lo + hi) >> 1;
            if (batch[mid] < g) lo = mid + 1; else hi = mid;
        }
        gptr[g] = lo;
    }
    // W2 (128x128 f32) -> bf16
    for (int i = t; i < 4096; i += 256) {
        const float4 w = ((const float4*)W2)[i];
        uint2 o; o.x = pack2(w.x, w.y); o.y = pack2(w.z, w.w);
        ((uint2*)W2bf)[i] = o;
    }
}

// ---- phase 3: bucketed append of packed (dstLocal<<16|src) ----
__global__ __launch_bounds__(256) void k_bfill(const int* __restrict__ ei,
                                               int* __restrict__ bcur,
                                               unsigned* __restrict__ col1,
                                               int E, int chunk, int NB) {
    __shared__ int bins[256];
    __shared__ int base[256];
    for (int t = threadIdx.x; t < NB; t += 256) bins[t] = 0;
    __syncthreads();
    const int e0 = blockIdx.x * chunk;
    int e1 = e0 + chunk; if (e1 > E) e1 = E;
    for (int j = e0 + (int)threadIdx.x; j < e1; j += 256)
        atomicAdd(&bins[ei[E + j] >> 8], 1);
    __syncthreads();
    for (int t = threadIdx.x; t < NB; t += 256) {
        base[t] = bins[t] ? atomicAdd(&bcur[t], bins[t]) : 0;
        bins[t] = 0;
    }
    __syncthreads();
    for (int j = e0 + (int)threadIdx.x; j < e1; j += 256) {
        int d = ei[E + j];
        int s = ei[j];
        int b = d >> 8;
        int pos = base[b] + atomicAdd(&bins[b], 1);
        col1[pos] = ((unsigned)(d & 255) << 16) | (unsigned)s;
    }
}

// ---- phase 4: per-bucket LDS sort -> exact CSR + dinv + xsb ----
__global__ __launch_bounds__(256) void k_bsort(const unsigned* __restrict__ col1,
                                               const int* __restrict__ bstart,
                                               int* __restrict__ col,
                                               int* __restrict__ rowptr,
                                               float* __restrict__ dinv,
                                               const float* __restrict__ x,
                                               unsigned short* __restrict__ xsb,
                                               int N) {
    __shared__ unsigned ec[BCAP];
    __shared__ int bins[256], sc[256];
    __shared__ float dvb[256];
    const int b = blockIdx.x, t = threadIdx.x;
    const int s0 = bstart[b];
    int cnt = bstart[b + 1] - s0;
    if (cnt > BCAP) cnt = BCAP;        // safety clamp (never hit for this E,N)
    for (int i = t; i < cnt; i += 256) ec[i] = col1[s0 + i];
    bins[t] = 0;
    __syncthreads();
    for (int i = t; i < cnt; i += 256) atomicAdd(&bins[ec[i] >> 16], 1);
    __syncthreads();
    const int v = bins[t];
    sc[t] = v;
    __syncthreads();
    for (int off = 1; off < 256; off <<= 1) {
        int add = (t >= off) ? sc[t - off] : 0;
        __syncthreads();
        sc[t] += add;
        __syncthreads();
    }
    const int ex = sc[t] - v;
    __syncthreads();
    sc[t] = ex;          // exclusive local offsets
    bins[t] = 0;         // reuse as per-node cursor
    const float dv = rsqrtf((float)(v + 1));
    dvb[t] = dv;
    const int n0 = b * 256;
    if (n0 + t < N) {
        rowptr[n0 + t] = s0 + ex;
        dinv[n0 + t] = dv;
    }
    __syncthreads();
    for (int i = t; i < cnt; i += 256) {
        unsigned e = ec[i];
        int dl = e >> 16;
        int p = sc[dl] + atomicAdd(&bins[dl], 1);
        col[s0 + p] = (int)(e & 0xffffu);
    }
    // xsb = bf16(x * dinv) for this bucket's nodes (coalesced)
    int nn = N - n0; if (nn > 256) nn = 256;
    const int lim = nn * 16;
    for (int i = t; i < lim; i += 256) {
        float vx = x[(size_t)n0 * 16 + i] * dvb[i >> 4];
        xsb[(size_t)n0 * 16 + i] = (unsigned short)(pack2(vx, 0.f) & 0xffffu);
    }
}

// ---- FUSED gat16 + l12: 64 nodes/block, 512 threads (8 waves), ~71 KB LDS,
//      2 blocks/CU. Wave w gathers nodes w*8..w*8+7 into arow, then
//      h1 = relu(dinv*(arow@W1)+b1); ht1b = bf16((h1@W2bf)*dinv). ----
__global__ __launch_bounds__(512, 4) void k_l12g(
        const int* __restrict__ rowptr, const int* __restrict__ col,
        const unsigned short* __restrict__ xsb,
        const float* __restrict__ dinv,
        const float* __restrict__ W1, const float* __restrict__ b1,
        const unsigned short* __restrict__ W2bf,
        unsigned short* __restrict__ ht1b, int N) {
    __shared__ __align__(16) unsigned short W2s[128 * 128];  // 32 KB bf16 [k][f]
    __shared__ __align__(16) float h1t[128 * 68];            // [k][j], 34 KB
    __shared__ __align__(16) float arow[64 * 16];
    __shared__ float dv[64];
    const int tid = threadIdx.x;
    const int n0 = blockIdx.x * 64;

    // stage pre-packed W2 (bf16, 32 KB)
    for (int i = tid; i < 2048; i += 512)
        ((uint4*)W2s)[i] = ((const uint4*)W2bf)[i];
    if (tid < 64) dv[tid] = (n0 + tid < N) ? dinv[n0 + tid] : 0.f;

    // gather: wave w -> nodes w*8..w*8+7; 16 edge-slots x 4 lanes x uint2
    {
        const int w = tid >> 6, lane = tid & 63;
        const int slot = lane >> 2, qq = lane & 3;
        for (int k = 0; k < 8; ++k) {
            const int j = w * 8 + k;
            const int n = n0 + j;
            float a[4] = {0.f, 0.f, 0.f, 0.f};
            if (n < N) {
                const int r0 = rowptr[n], r1 = rowptr[n + 1];
                int jj = r0 + slot;
                while (jj + 16 < r1) {
                    int s0 = col[jj], s1 = col[jj + 16];
                    bf4acc(*(const uint2*)(xsb + (size_t)s0 * 16 + qq * 4), a);
                    bf4acc(*(const uint2*)(xsb + (size_t)s1 * 16 + qq * 4), a);
                    jj += 32;
                }
                if (jj < r1)
                    bf4acc(*(const uint2*)(xsb + (size_t)col[jj] * 16 + qq * 4), a);
            }
#pragma unroll
            for (int m = 4; m < 64; m <<= 1)
#pragma unroll
                for (int i = 0; i < 4; ++i) a[i] += __shfl_xor(a[i], m);
            if (slot == 0) {
                if (n < N) {   // self loop
                    bf4acc(*(const uint2*)(xsb + (size_t)n * 16 + qq * 4), a);
                    *(float4*)&arow[j * 16 + qq * 4] = make_float4(a[0], a[1], a[2], a[3]);
                } else {
                    *(float4*)&arow[j * 16 + qq * 4] = make_float4(0.f, 0.f, 0.f, 0.f);
                }
            }
        }
    }
    const int f = tid & 127, jg = tid >> 7;
    float w1r[16];
#pragma unroll
    for (int k = 0; k < 16; ++k) w1r[k] = W1[k * 128 + f];
    const float bias = b1[f];
    __syncthreads();

#pragma unroll 4
    for (int j = jg * 16; j < jg * 16 + 16; ++j) {
        float s = 0.f;
#pragma unroll
        for (int k = 0; k < 16; ++k) s += arow[j * 16 + k] * w1r[k];
        h1t[f * 68 + j] = fmaxf(dv[j] * s + bias, 0.f);
    }
    __syncthreads();

    const int f0 = (tid & 31) * 4;
    const int j0 = (tid >> 5) * 4;
    float acc[4][4];
#pragma unroll
    for (int a = 0; a < 4; ++a)
#pragma unroll
        for (int b = 0; b < 4; ++b) acc[a][b] = 0.f;
#pragma unroll 4
    for (int k = 0; k < 128; ++k) {
        const uint2 wv = *(const uint2*)&W2s[k * 128 + f0];
        const float4 w = bf4(wv);
        const float4 h = *(const float4*)&h1t[k * 68 + j0];
        acc[0][0] += h.x * w.x; acc[0][1] += h.x * w.y; acc[0][2] += h.x * w.z; acc[0][3] += h.x * w.w;
        acc[1][0] += h.y * w.x; acc[1][1] += h.y * w.y; acc[1][2] += h.y * w.z; acc[1][3] += h.y * w.w;
        acc[2][0] += h.z * w.x; acc[2][1] += h.z * w.y; acc[2][2] += h.z * w.z; acc[2][3] += h.z * w.w;
        acc[3][0] += h.w * w.x; acc[3][1] += h.w * w.y; acc[3][2] += h.w * w.z; acc[3][3] += h.w * w.w;
    }
#pragma unroll
    for (int a = 0; a < 4; ++a) {
        const int n = n0 + j0 + a;
        if (n < N) {
            const float d = dv[j0 + a];
            uint2 o;
            o.x = pack2(acc[a][0] * d, acc[a][1] * d);
            o.y = pack2(acc[a][2] * d, acc[a][3] * d);
            *(uint2*)(ht1b + (size_t)n * 128 + f0) = o;
        }
    }
}

// Wave/node gather (2 halves x 32 lanes x uint2, 4x unroll -> 8 rows in flight),
// then 4-node LDS merge -> ~1 atomic set per block (batch sorted).
__global__ __launch_bounds__(256) void k_gat128pool(
        const int* __restrict__ rowptr, const int* __restrict__ col,
        const unsigned short* __restrict__ ht1b,
        const float* __restrict__ dinv, const float* __restrict__ b2,
        const int* __restrict__ batch, float* __restrict__ gsum, int N) {
    __shared__ __align__(16) float h2s[4][128];
    __shared__ int bats[4];
    const int wave = threadIdx.x >> 6, lane = threadIdx.x & 63;
    const int half = lane >> 5, q = lane & 31;
    const int n = blockIdx.x * 4 + wave;
    float a[4] = {0.f, 0.f, 0.f, 0.f};
    if (n < N) {
        const int r0 = rowptr[n], r1 = rowptr[n + 1];
        int j = r0 + half;
        while (j + 6 < r1) {
            int s0 = col[j], s1 = col[j + 2], s2 = col[j + 4], s3 = col[j + 6];
            uint2 u0 = *(const uint2*)(ht1b + (size_t)s0 * 128 + q * 4);
            uint2 u1 = *(const uint2*)(ht1b + (size_t)s1 * 128 + q * 4);
            uint2 u2 = *(const uint2*)(ht1b + (size_t)s2 * 128 + q * 4);
            uint2 u3 = *(const uint2*)(ht1b + (size_t)s3 * 128 + q * 4);
            bf4acc(u0, a); bf4acc(u1, a); bf4acc(u2, a); bf4acc(u3, a);
            j += 8;
        }
        while (j < r1) {
            bf4acc(*(const uint2*)(ht1b + (size_t)col[j] * 128 + q * 4), a);
            j += 2;
        }
        if (half == 0)  // self loop
            bf4acc(*(const uint2*)(ht1b + (size_t)n * 128 + q * 4), a);
    }
#pragma unroll
    for (int i = 0; i < 4; ++i) a[i] += __shfl_xor(a[i], 32);
    if (half == 0) {
        if (n < N) {
            const float d = dinv[n];
            const float4 bb = *(const float4*)(b2 + q * 4);
            h2s[wave][q * 4 + 0] = fmaxf(a[0] * d + bb.x, 0.f);
            h2s[wave][q * 4 + 1] = fmaxf(a[1] * d + bb.y, 0.f);
            h2s[wave][q * 4 + 2] = fmaxf(a[2] * d + bb.z, 0.f);
            h2s[wave][q * 4 + 3] = fmaxf(a[3] * d + bb.w, 0.f);
            if (q == 0) bats[wave] = batch[n];
        } else {
            h2s[wave][q * 4 + 0] = 0.f; h2s[wave][q * 4 + 1] = 0.f;
            h2s[wave][q * 4 + 2] = 0.f; h2s[wave][q * 4 + 3] = 0.f;
            if (q == 0) bats[wave] = -1;
        }
    }
    __syncthreads();
    if (threadIdx.x < 32) {
        const int qq = threadIdx.x;
        const int b0 = bats[0], b1 = bats[1], b2i = bats[2], b3 = bats[3];
        float4 r0v = *(const float4*)&h2s[0][qq * 4];
        float4 r1v = *(const float4*)&h2s[1][qq * 4];
        float4 r2v = *(const float4*)&h2s[2][qq * 4];
        float4 r3v = *(const float4*)&h2s[3][qq * 4];
        bool m1 = false, m2 = false, m3 = false;
        if (b0 >= 0) {
            float4 s = r0v;
            if (b1 == b0) { s.x += r1v.x; s.y += r1v.y; s.z += r1v.z; s.w += r1v.w; m1 = true; }
            if (b2i == b0) { s.x += r2v.x; s.y += r2v.y; s.z += r2v.z; s.w += r2v.w; m2 = true; }
            if (b3 == b0) { s.x += r3v.x; s.y += r3v.y; s.z += r3v.z; s.w += r3v.w; m3 = true; }
            float* gs = gsum + (size_t)b0 * 128 + qq * 4;
            unsafeAtomicAdd(gs + 0, s.x); unsafeAtomicAdd(gs + 1, s.y);
            unsafeAtomicAdd(gs + 2, s.z); unsafeAtomicAdd(gs + 3, s.w);
        }
        if (!m1 && b1 >= 0) {
            float4 s = r1v;
            if (b2i == b1) { s.x += r2v.x; s.y += r2v.y; s.z += r2v.z; s.w += r2v.w; m2 = true; }
            if (b3 == b1) { s.x += r3v.x; s.y += r3v.y; s.z += r3v.z; s.w += r3v.w; m3 = true; }
            float* gs = gsum + (size_t)b1 * 128 + qq * 4;
            unsafeAtomicAdd(gs + 0, s.x); unsafeAtomicAdd(gs + 1, s.y);
            unsafeAtomicAdd(gs + 2, s.z); unsafeAtomicAdd(gs + 3, s.w);
        }
        if (!m2 && b2i >= 0) {
            float4 s = r2v;
            if (b3 == b2i) { s.x += r3v.x; s.y += r3v.y; s.z += r3v.z; s.w += r3v.w; m3 = true; }
            float* gs = gsum + (size_t)b2i * 128 + qq * 4;
            unsafeAtomicAdd(gs + 0, s.x); unsafeAtomicAdd(gs + 1, s.y);
            unsafeAtomicAdd(gs + 2, s.z); unsafeAtomicAdd(gs + 3, s.w);
        }
        if (!m3 && b3 >= 0) {
            float* gs = gsum + (size_t)b3 * 128 + qq * 4;
            unsafeAtomicAdd(gs + 0, r3v.x); unsafeAtomicAdd(gs + 1, r3v.y);
            unsafeAtomicAdd(gs + 2, r3v.z); unsafeAtomicAdd(gs + 3, r3v.w);
        }
    }
}

__global__ __launch_bounds__(128) void k_head(
        const float* __restrict__ gsum, const int* __restrict__ gptr,
        const float* __restrict__ Wlab, const float* __restrict__ blab,
        const float* __restrict__ Wd1, const float* __restrict__ bd1,
        const float* __restrict__ Wd2, const float* __restrict__ bd2,
        float* __restrict__ out, int G) {
    __shared__ float sp[128];
    __shared__ float red[128];
    __shared__ float hd[64];
    const int g = blockIdx.x, t = threadIdx.x;
    const float cnt = (float)(gptr[g + 1] - gptr[g]);
    const float invc = 1.f / fmaxf(cnt, 1.f);
    const float pooled = gsum[g * 128 + t] * invc;
    sp[t] = pooled;
    red[t] = pooled * Wlab[t];
    __syncthreads();
    for (int off = 64; off > 0; off >>= 1) {
        if (t < off) red[t] += red[t + off];
        __syncthreads();
    }
    if (t == 0) {
        float z = red[0] + blab[0];
        out[g] = 1.f / (1.f + expf(-z));
    }
    if (t < 64) {
        float s = bd1[t];
        for (int f = 0; f < 128; ++f) s += sp[f] * Wd1[f * 64 + t];
        hd[t] = fmaxf(s, 0.f);
    }
    __syncthreads();
    if (t < 2) {
        float s = bd2[t];
        for (int j = 0; j < 64; ++j) s += hd[j] * Wd2[j * 2 + t];
        out[G + g * 2 + t] = s;
    }
}

extern "C" void kernel_launch(void* const* d_in, const int* in_sizes, int n_in,
                              void* d_out, int out_size, void* d_ws, size_t ws_size,
                              hipStream_t stream) {
    const float* x     = (const float*)d_in[0];
    const int*   ei    = (const int*)d_in[1];   // [2,E]: ei[e]=src, ei[E+e]=dst
    const int*   batch = (const int*)d_in[2];
    const float* W1    = (const float*)d_in[3];
    const float* b1    = (const float*)d_in[4];
    const float* W2    = (const float*)d_in[5];
    const float* b2    = (const float*)d_in[6];
    const float* Wlab  = (const float*)d_in[7];
    const float* blab  = (const float*)d_in[8];
    const float* Wd1   = (const float*)d_in[9];
    const float* bd1   = (const float*)d_in[10];
    const float* Wd2   = (const float*)d_in[11];
    const float* bd2   = (const float*)d_in[12];
    float* out = (float*)d_out;

    const int N = in_sizes[0] / 16;
    const int E = in_sizes[1] / 2;
    const int G = out_size / 3;
    const int NB = (N + 255) >> 8;             // node buckets of 256

    char* p = (char*)d_ws;
    auto carve = [&](size_t bytes) {
        void* r = (void*)p;
        p += (bytes + 255) & ~(size_t)255;
        return r;
    };
    const int FB = 256;                        // blocks for bhist/bfill
    int*      bcnt2  = (int*)     carve((size_t)FB * NB * 4);
    int*      bstart = (int*)     carve((size_t)(NB + 1) * 4);
    int*      bcur   = (int*)     carve((size_t)NB * 4);
    unsigned* col1   = (unsigned*)carve((size_t)E * 4);
    int*      col    = (int*)     carve((size_t)E * 4);
    int*      rowptr = (int*)     carve((size_t)(N + 1) * 4);
    int*      gptr   = (int*)     carve((size_t)(G + 1) * 4);
    float*    dinv   = (float*)   carve((size_t)N * 4);
    unsigned short* xsb  = (unsigned short*)carve((size_t)N * 16 * 2);
    unsigned short* W2bf = (unsigned short*)carve(128 * 128 * 2);
    unsigned short* ht1b = (unsigned short*)carve((size_t)N * 128 * 2);
    float*    gsum   = (float*)   carve((size_t)G * 128 * 4);

    const int chunk = (E + FB - 1) / FB;

    k_bhist  <<<FB, 256, 0, stream>>>(ei, bcnt2, E, chunk, NB);
    k_mid    <<<1, 256, 0, stream>>>(bcnt2, bstart, bcur, batch, gptr, gsum,
                                     rowptr, W2, W2bf, NB, FB, E, N, G);
    k_bfill  <<<FB, 256, 0, stream>>>(ei, bcur, col1, E, chunk, NB);
    k_bsort  <<<NB, 256, 0, stream>>>(col1, bstart, col, rowptr, dinv, x, xsb, N);
    k_l12g   <<<(N + 63) / 64, 512, 0, stream>>>(rowptr, col, xsb, dinv,
                                                 W1, b1, W2bf, ht1b, N);
    k_gat128pool<<<(N + 3) / 4, 256, 0, stream>>>(rowptr, col, ht1b, dinv, b2, batch, gsum, N);
    k_head   <<<G, 128, 0, stream>>>(gsum, gptr, Wlab, blab, Wd1, bd1, Wd2, bd2, out, G);
}

// Round 10
// 269.076 us; speedup vs baseline: 1.2598x; 1.2598x over previous
//
#include <hip/hip_runtime.h>
#include <math.h>

// GCN forward, CSR-gather; bf16 xs/W2/ht1; block-aggregated pooling.
// CSR build = two-level bucket sort (append-order writes only).
// Requires N <= 65536 (src packed in 16 bits) -- holds for N=50000.
// Round-10 note: round 9's single-block k_mid serialized a 64K-load
// reduction + 256KB zeroing on one CU (86 us). Reverted to memset+global
// atomics (L2-resident, round-8-verified) and spread the prep work as
// grid-stride tails over k_bhist's 256 blocks.
// Pipeline (8 dispatches):
//   memset    : bcnt = 0 (784 B)
//   k_bhist   : LDS hist -> 196 global atomics; tails: gsum=0, gptr
//               binary-search, W2bf = bf16(W2)
//   k_scan196 : 1 block: exclusive scan -> bstart/bcur; rowptr[N]=E
//   k_bfill   : per-block LDS hist + reservation; append (dstLocal<<16|src)
//   k_bsort   : block/bucket LDS 256-bin sort -> rowptr, dinv, sorted col;
//               + xsb = bf16(x*dinv) for its own 256 nodes
//   k_l12g    : FUSED: 8 waves gather rank-16 neighborhoods -> arow LDS;
//               h1 = relu(dinv*(arow@W1)+b1); ht1b = bf16((h1@W2bf)*dinv)
//   k_gat128pool : wave/node gather, 4-node LDS merge -> ~1 atomic set/block
//   k_head    : pooled = gsum/cnt; label/domain heads

#define BCAP 24576   // max edges per 256-node bucket (mean ~8.2K; 3x headroom)

__device__ __forceinline__ float4 bf4(uint2 u) {
    return make_float4(__uint_as_float(u.x << 16),
                       __uint_as_float(u.x & 0xffff0000u),
                       __uint_as_float(u.y << 16),
                       __uint_as_float(u.y & 0xffff0000u));
}

__device__ __forceinline__ void bf4acc(uint2 u, float* a) {
    a[0] += __uint_as_float(u.x << 16);
    a[1] += __uint_as_float(u.x & 0xffff0000u);
    a[2] += __uint_as_float(u.y << 16);
    a[3] += __uint_as_float(u.y & 0xffff0000u);
}

__device__ __forceinline__ unsigned pack2(float a, float b) {   // RNE bf16 pair
    unsigned ua = __float_as_uint(a), ub = __float_as_uint(b);
    ua = (ua + 0x7fffu + ((ua >> 16) & 1u)) >> 16;
    ub = (ub + 0x7fffu + ((ub >> 16) & 1u)) >> 16;
    return ua | (ub << 16);
}

// ---- phase 1: bucket histogram (global atomics, L2-resident) + prep tails ----
__global__ __launch_bounds__(256) void k_bhist(
        const int* __restrict__ ei, int* __restrict__ bcnt,
        const int* __restrict__ batch, int* __restrict__ gptr,
        float* __restrict__ gsum, const float* __restrict__ W2,
        unsigned short* __restrict__ W2bf,
        int E, int chunk, int NB, int N, int G) {
    __shared__ int bins[256];
    for (int t = threadIdx.x; t < NB; t += 256) bins[t] = 0;
    __syncthreads();
    const int e0 = blockIdx.x * chunk;
    int e1 = e0 + chunk; if (e1 > E) e1 = E;
    for (int j = e0 + (int)threadIdx.x; j < e1; j += 256)
        atomicAdd(&bins[ei[E + j] >> 8], 1);
    __syncthreads();
    for (int t = threadIdx.x; t < NB; t += 256)
        if (bins[t]) atomicAdd(&bcnt[t], bins[t]);

    // distributed prep tails
    const int gid = blockIdx.x * 256 + threadIdx.x;
    const int gsz = gridDim.x * 256;
    for (int i = gid; i < G * 32; i += gsz)        // gsum = 0 (float4)
        ((float4*)gsum)[i] = make_float4(0.f, 0.f, 0.f, 0.f);
    for (int i = gid; i < 4096; i += gsz) {        // W2 -> bf16
        const float4 w = ((const float4*)W2)[i];
        uint2 o; o.x = pack2(w.x, w.y); o.y = pack2(w.z, w.w);
        ((uint2*)W2bf)[i] = o;
    }
    for (int g = gid; g <= G; g += gsz) {          // gptr = lower_bound(batch,g)
        int lo = 0, hi = N;
        while (lo < hi) {
            int mid = (lo + hi) >> 1;
            if (batch[mid] < g) lo = mid + 1; else hi = mid;
        }
        gptr[g] = lo;
    }
}

// ---- phase 2: scan NB bucket counts (NB <= 256), 1 block ----
__global__ void k_scan196(const int* __restrict__ bcnt, int* __restrict__ bstart,
                          int* __restrict__ bcur, int* __restrict__ rowptr,
                          int NB, int E, int N) {
    __shared__ int s[256];
    int t = threadIdx.x;
    int v = (t < NB) ? bcnt[t] : 0;
    s[t] = v;
    __syncthreads();
    for (int off = 1; off < 256; off <<= 1) {
        int add = (t >= off) ? s[t - off] : 0;
        __syncthreads();
        s[t] += add;
        __syncthreads();
    }
    if (t < NB) { bstart[t] = s[t] - v; bcur[t] = s[t] - v; }
    if (t == 0) { bstart[NB] = E; rowptr[N] = E; }
}

// ---- phase 3: bucketed append of packed (dstLocal<<16|src) ----
__global__ __launch_bounds__(256) void k_bfill(const int* __restrict__ ei,
                                               int* __restrict__ bcur,
                                               unsigned* __restrict__ col1,
                                               int E, int chunk, int NB) {
    __shared__ int bins[256];
    __shared__ int base[256];
    for (int t = threadIdx.x; t < NB; t += 256) bins[t] = 0;
    __syncthreads();
    const int e0 = blockIdx.x * chunk;
    int e1 = e0 + chunk; if (e1 > E) e1 = E;
    for (int j = e0 + (int)threadIdx.x; j < e1; j += 256)
        atomicAdd(&bins[ei[E + j] >> 8], 1);
    __syncthreads();
    for (int t = threadIdx.x; t < NB; t += 256) {
        base[t] = bins[t] ? atomicAdd(&bcur[t], bins[t]) : 0;
        bins[t] = 0;
    }
    __syncthreads();
    for (int j = e0 + (int)threadIdx.x; j < e1; j += 256) {
        int d = ei[E + j];
        int s = ei[j];
        int b = d >> 8;
        int pos = base[b] + atomicAdd(&bins[b], 1);
        col1[pos] = ((unsigned)(d & 255) << 16) | (unsigned)s;
    }
}

// ---- phase 4: per-bucket LDS sort -> exact CSR + dinv + xsb ----
__global__ __launch_bounds__(256) void k_bsort(const unsigned* __restrict__ col1,
                                               const int* __restrict__ bstart,
                                               int* __restrict__ col,
                                               int* __restrict__ rowptr,
                                               float* __restrict__ dinv,
                                               const float* __restrict__ x,
                                               unsigned short* __restrict__ xsb,
                                               int N) {
    __shared__ unsigned ec[BCAP];
    __shared__ int bins[256], sc[256];
    __shared__ float dvb[256];
    const int b = blockIdx.x, t = threadIdx.x;
    const int s0 = bstart[b];
    int cnt = bstart[b + 1] - s0;
    if (cnt > BCAP) cnt = BCAP;        // safety clamp (never hit for this E,N)
    for (int i = t; i < cnt; i += 256) ec[i] = col1[s0 + i];
    bins[t] = 0;
    __syncthreads();
    for (int i = t; i < cnt; i += 256) atomicAdd(&bins[ec[i] >> 16], 1);
    __syncthreads();
    const int v = bins[t];
    sc[t] = v;
    __syncthreads();
    for (int off = 1; off < 256; off <<= 1) {
        int add = (t >= off) ? sc[t - off] : 0;
        __syncthreads();
        sc[t] += add;
        __syncthreads();
    }
    const int ex = sc[t] - v;
    __syncthreads();
    sc[t] = ex;          // exclusive local offsets
    bins[t] = 0;         // reuse as per-node cursor
    const float dv = rsqrtf((float)(v + 1));
    dvb[t] = dv;
    const int n0 = b * 256;
    if (n0 + t < N) {
        rowptr[n0 + t] = s0 + ex;
        dinv[n0 + t] = dv;
    }
    __syncthreads();
    for (int i = t; i < cnt; i += 256) {
        unsigned e = ec[i];
        int dl = e >> 16;
        int p = sc[dl] + atomicAdd(&bins[dl], 1);
        col[s0 + p] = (int)(e & 0xffffu);
    }
    // xsb = bf16(x * dinv) for this bucket's nodes (coalesced)
    int nn = N - n0; if (nn > 256) nn = 256;
    const int lim = nn * 16;
    for (int i = t; i < lim; i += 256) {
        float vx = x[(size_t)n0 * 16 + i] * dvb[i >> 4];
        xsb[(size_t)n0 * 16 + i] = (unsigned short)(pack2(vx, 0.f) & 0xffffu);
    }
}

// ---- FUSED gat16 + l12: 64 nodes/block, 512 threads (8 waves), ~71 KB LDS,
//      2 blocks/CU. Wave w gathers nodes w*8..w*8+7 into arow, then
//      h1 = relu(dinv*(arow@W1)+b1); ht1b = bf16((h1@W2bf)*dinv). ----
__global__ __launch_bounds__(512, 4) void k_l12g(
        const int* __restrict__ rowptr, const int* __restrict__ col,
        const unsigned short* __restrict__ xsb,
        const float* __restrict__ dinv,
        const float* __restrict__ W1, const float* __restrict__ b1,
        const unsigned short* __restrict__ W2bf,
        unsigned short* __restrict__ ht1b, int N) {
    __shared__ __align__(16) unsigned short W2s[128 * 128];  // 32 KB bf16 [k][f]
    __shared__ __align__(16) float h1t[128 * 68];            // [k][j], 34 KB
    __shared__ __align__(16) float arow[64 * 16];
    __shared__ float dv[64];
    const int tid = threadIdx.x;
    const int n0 = blockIdx.x * 64;

    // stage pre-packed W2 (bf16, 32 KB)
    for (int i = tid; i < 2048; i += 512)
        ((uint4*)W2s)[i] = ((const uint4*)W2bf)[i];
    if (tid < 64) dv[tid] = (n0 + tid < N) ? dinv[n0 + tid] : 0.f;

    // gather: wave w -> nodes w*8..w*8+7; 16 edge-slots x 4 lanes x uint2
    {
        const int w = tid >> 6, lane = tid & 63;
        const int slot = lane >> 2, qq = lane & 3;
        for (int k = 0; k < 8; ++k) {
            const int j = w * 8 + k;
            const int n = n0 + j;
            float a[4] = {0.f, 0.f, 0.f, 0.f};
            if (n < N) {
                const int r0 = rowptr[n], r1 = rowptr[n + 1];
                int jj = r0 + slot;
                while (jj + 16 < r1) {
                    int s0 = col[jj], s1 = col[jj + 16];
                    bf4acc(*(const uint2*)(xsb + (size_t)s0 * 16 + qq * 4), a);
                    bf4acc(*(const uint2*)(xsb + (size_t)s1 * 16 + qq * 4), a);
                    jj += 32;
                }
                if (jj < r1)
                    bf4acc(*(const uint2*)(xsb + (size_t)col[jj] * 16 + qq * 4), a);
            }
#pragma unroll
            for (int m = 4; m < 64; m <<= 1)
#pragma unroll
                for (int i = 0; i < 4; ++i) a[i] += __shfl_xor(a[i], m);
            if (slot == 0) {
                if (n < N) {   // self loop
                    bf4acc(*(const uint2*)(xsb + (size_t)n * 16 + qq * 4), a);
                    *(float4*)&arow[j * 16 + qq * 4] = make_float4(a[0], a[1], a[2], a[3]);
                } else {
                    *(float4*)&arow[j * 16 + qq * 4] = make_float4(0.f, 0.f, 0.f, 0.f);
                }
            }
        }
    }
    const int f = tid & 127, jg = tid >> 7;
    float w1r[16];
#pragma unroll
    for (int k = 0; k < 16; ++k) w1r[k] = W1[k * 128 + f];
    const float bias = b1[f];
    __syncthreads();

#pragma unroll 4
    for (int j = jg * 16; j < jg * 16 + 16; ++j) {
        float s = 0.f;
#pragma unroll
        for (int k = 0; k < 16; ++k) s += arow[j * 16 + k] * w1r[k];
        h1t[f * 68 + j] = fmaxf(dv[j] * s + bias, 0.f);
    }
    __syncthreads();

    const int f0 = (tid & 31) * 4;
    const int j0 = (tid >> 5) * 4;
    float acc[4][4];
#pragma unroll
    for (int a = 0; a < 4; ++a)
#pragma unroll
        for (int b = 0; b < 4; ++b) acc[a][b] = 0.f;
#pragma unroll 4
    for (int k = 0; k < 128; ++k) {
        const uint2 wv = *(const uint2*)&W2s[k * 128 + f0];
        const float4 w = bf4(wv);
        const float4 h = *(const float4*)&h1t[k * 68 + j0];
        acc[0][0] += h.x * w.x; acc[0][1] += h.x * w.y; acc[0][2] += h.x * w.z; acc[0][3] += h.x * w.w;
        acc[1][0] += h.y * w.x; acc[1][1] += h.y * w.y; acc[1][2] += h.y * w.z; acc[1][3] += h.y * w.w;
        acc[2][0] += h.z * w.x; acc[2][1] += h.z * w.y; acc[2][2] += h.z * w.z; acc[2][3] += h.z * w.w;
        acc[3][0] += h.w * w.x; acc[3][1] += h.w * w.y; acc[3][2] += h.w * w.z; acc[3][3] += h.w * w.w;
    }
#pragma unroll
    for (int a = 0; a < 4; ++a) {
        const int n = n0 + j0 + a;
        if (n < N) {
            const float d = dv[j0 + a];
            uint2 o;
            o.x = pack2(acc[a][0] * d, acc[a][1] * d);
            o.y = pack2(acc[a][2] * d, acc[a][3] * d);
            *(uint2*)(ht1b + (size_t)n * 128 + f0) = o;
        }
    }
}

// Wave/node gather (2 halves x 32 lanes x uint2, 4x unroll -> 8 rows in flight),
// then 4-node LDS merge -> ~1 atomic set per block (batch sorted).
__global__ __launch_bounds__(256) void k_gat128pool(
        const int* __restrict__ rowptr, const int* __restrict__ col,
        const unsigned short* __restrict__ ht1b,
        const float* __restrict__ dinv, const float* __restrict__ b2,
        const int* __restrict__ batch, float* __restrict__ gsum, int N) {
    __shared__ __align__(16) float h2s[4][128];
    __shared__ int bats[4];
    const int wave = threadIdx.x >> 6, lane = threadIdx.x & 63;
    const int half = lane >> 5, q = lane & 31;
    const int n = blockIdx.x * 4 + wave;
    float a[4] = {0.f, 0.f, 0.f, 0.f};
    if (n < N) {
        const int r0 = rowptr[n], r1 = rowptr[n + 1];
        int j = r0 + half;
        while (j + 6 < r1) {
            int s0 = col[j], s1 = col[j + 2], s2 = col[j + 4], s3 = col[j + 6];
            uint2 u0 = *(const uint2*)(ht1b + (size_t)s0 * 128 + q * 4);
            uint2 u1 = *(const uint2*)(ht1b + (size_t)s1 * 128 + q * 4);
            uint2 u2 = *(const uint2*)(ht1b + (size_t)s2 * 128 + q * 4);
            uint2 u3 = *(const uint2*)(ht1b + (size_t)s3 * 128 + q * 4);
            bf4acc(u0, a); bf4acc(u1, a); bf4acc(u2, a); bf4acc(u3, a);
            j += 8;
        }
        while (j < r1) {
            bf4acc(*(const uint2*)(ht1b + (size_t)col[j] * 128 + q * 4), a);
            j += 2;
        }
        if (half == 0)  // self loop
            bf4acc(*(const uint2*)(ht1b + (size_t)n * 128 + q * 4), a);
    }
#pragma unroll
    for (int i = 0; i < 4; ++i) a[i] += __shfl_xor(a[i], 32);
    if (half == 0) {
        if (n < N) {
            const float d = dinv[n];
            const float4 bb = *(const float4*)(b2 + q * 4);
            h2s[wave][q * 4 + 0] = fmaxf(a[0] * d + bb.x, 0.f);
            h2s[wave][q * 4 + 1] = fmaxf(a[1] * d + bb.y, 0.f);
            h2s[wave][q * 4 + 2] = fmaxf(a[2] * d + bb.z, 0.f);
            h2s[wave][q * 4 + 3] = fmaxf(a[3] * d + bb.w, 0.f);
            if (q == 0) bats[wave] = batch[n];
        } else {
            h2s[wave][q * 4 + 0] = 0.f; h2s[wave][q * 4 + 1] = 0.f;
            h2s[wave][q * 4 + 2] = 0.f; h2s[wave][q * 4 + 3] = 0.f;
            if (q == 0) bats[wave] = -1;
        }
    }
    __syncthreads();
    if (threadIdx.x < 32) {
        const int qq = threadIdx.x;
        const int b0 = bats[0], b1 = bats[1], b2i = bats[2], b3 = bats[3];
        float4 r0v = *(const float4*)&h2s[0][qq * 4];
        float4 r1v = *(const float4*)&h2s[1][qq * 4];
        float4 r2v = *(const float4*)&h2s[2][qq * 4];
        float4 r3v = *(const float4*)&h2s[3][qq * 4];
        bool m1 = false, m2 = false, m3 = false;
        if (b0 >= 0) {
            float4 s = r0v;
            if (b1 == b0) { s.x += r1v.x; s.y += r1v.y; s.z += r1v.z; s.w += r1v.w; m1 = true; }
            if (b2i == b0) { s.x += r2v.x; s.y += r2v.y; s.z += r2v.z; s.w += r2v.w; m2 = true; }
            if (b3 == b0) { s.x += r3v.x; s.y += r3v.y; s.z += r3v.z; s.w += r3v.w; m3 = true; }
            float* gs = gsum + (size_t)b0 * 128 + qq * 4;
            unsafeAtomicAdd(gs + 0, s.x); unsafeAtomicAdd(gs + 1, s.y);
            unsafeAtomicAdd(gs + 2, s.z); unsafeAtomicAdd(gs + 3, s.w);
        }
        if (!m1 && b1 >= 0) {
            float4 s = r1v;
            if (b2i == b1) { s.x += r2v.x; s.y += r2v.y; s.z += r2v.z; s.w += r2v.w; m2 = true; }
            if (b3 == b1) { s.x += r3v.x; s.y += r3v.y; s.z += r3v.z; s.w += r3v.w; m3 = true; }
            float* gs = gsum + (size_t)b1 * 128 + qq * 4;
            unsafeAtomicAdd(gs + 0, s.x); unsafeAtomicAdd(gs + 1, s.y);
            unsafeAtomicAdd(gs + 2, s.z); unsafeAtomicAdd(gs + 3, s.w);
        }
        if (!m2 && b2i >= 0) {
            float4 s = r2v;
            if (b3 == b2i) { s.x += r3v.x; s.y += r3v.y; s.z += r3v.z; s.w += r3v.w; m3 = true; }
            float* gs = gsum + (size_t)b2i * 128 + qq * 4;
            unsafeAtomicAdd(gs + 0, s.x); unsafeAtomicAdd(gs + 1, s.y);
            unsafeAtomicAdd(gs + 2, s.z); unsafeAtomicAdd(gs + 3, s.w);
        }
        if (!m3 && b3 >= 0) {
            float* gs = gsum + (size_t)b3 * 128 + qq * 4;
            unsafeAtomicAdd(gs + 0, r3v.x); unsafeAtomicAdd(gs + 1, r3v.y);
            unsafeAtomicAdd(gs + 2, r3v.z); unsafeAtomicAdd(gs + 3, r3v.w);
        }
    }
}

__global__ __launch_bounds__(128) void k_head(
        const float* __restrict__ gsum, const int* __restrict__ gptr,
        const float* __restrict__ Wlab, const float* __restrict__ blab,
        const float* __restrict__ Wd1, const float* __restrict__ bd1,
        const float* __restrict__ Wd2, const float* __restrict__ bd2,
        float* __restrict__ out, int G) {
    __shared__ float sp[128];
    __shared__ float red[128];
    __shared__ float hd[64];
    const int g = blockIdx.x, t = threadIdx.x;
    const float cnt = (float)(gptr[g + 1] - gptr[g]);
    const float invc = 1.f / fmaxf(cnt, 1.f);
    const float pooled = gsum[g * 128 + t] * invc;
    sp[t] = pooled;
    red[t] = pooled * Wlab[t];
    __syncthreads();
    for (int off = 64; off > 0; off >>= 1) {
        if (t < off) red[t] += red[t + off];
        __syncthreads();
    }
    if (t == 0) {
        float z = red[0] + blab[0];
        out[g] = 1.f / (1.f + expf(-z));
    }
    if (t < 64) {
        float s = bd1[t];
        for (int f = 0; f < 128; ++f) s += sp[f] * Wd1[f * 64 + t];
        hd[t] = fmaxf(s, 0.f);
    }
    __syncthreads();
    if (t < 2) {
        float s = bd2[t];
        for (int j = 0; j < 64; ++j) s += hd[j] * Wd2[j * 2 + t];
        out[G + g * 2 + t] = s;
    }
}

extern "C" void kernel_launch(void* const* d_in, const int* in_sizes, int n_in,
                              void* d_out, int out_size, void* d_ws, size_t ws_size,
                              hipStream_t stream) {
    const float* x     = (const float*)d_in[0];
    const int*   ei    = (const int*)d_in[1];   // [2,E]: ei[e]=src, ei[E+e]=dst
    const int*   batch = (const int*)d_in[2];
    const float* W1    = (const float*)d_in[3];
    const float* b1    = (const float*)d_in[4];
    const float* W2    = (const float*)d_in[5];
    const float* b2    = (const float*)d_in[6];
    const float* Wlab  = (const float*)d_in[7];
    const float* blab  = (const float*)d_in[8];
    const float* Wd1   = (const float*)d_in[9];
    const float* bd1   = (const float*)d_in[10];
    const float* Wd2   = (const float*)d_in[11];
    const float* bd2   = (const float*)d_in[12];
    float* out = (float*)d_out;

    const int N = in_sizes[0] / 16;
    const int E = in_sizes[1] / 2;
    const int G = out_size / 3;
    const int NB = (N + 255) >> 8;             // node buckets of 256

    char* p = (char*)d_ws;
    auto carve = [&](size_t bytes) {
        void* r = (void*)p;
        p += (bytes + 255) & ~(size_t)255;
        return r;
    };
    int*      bcnt   = (int*)     carve(256 * 4);
    int*      bstart = (int*)     carve((size_t)(NB + 1) * 4);
    int*      bcur   = (int*)     carve((size_t)NB * 4);
    unsigned* col1   = (unsigned*)carve((size_t)E * 4);
    int*      col    = (int*)     carve((size_t)E * 4);
    int*      rowptr = (int*)     carve((size_t)(N + 1) * 4);
    int*      gptr   = (int*)     carve((size_t)(G + 1) * 4);
    float*    dinv   = (float*)   carve((size_t)N * 4);
    unsigned short* xsb  = (unsigned short*)carve((size_t)N * 16 * 2);
    unsigned short* W2bf = (unsigned short*)carve(128 * 128 * 2);
    unsigned short* ht1b = (unsigned short*)carve((size_t)N * 128 * 2);
    float*    gsum   = (float*)   carve((size_t)G * 128 * 4);

    const int FB = 256;                        // blocks for bhist/bfill
    const int chunk = (E + FB - 1) / FB;

    hipMemsetAsync(bcnt, 0, 256 * 4, stream);
    k_bhist  <<<FB, 256, 0, stream>>>(ei, bcnt, batch, gptr, gsum, W2, W2bf,
                                      E, chunk, NB, N, G);
    k_scan196<<<1, 256, 0, stream>>>(bcnt, bstart, bcur, rowptr, NB, E, N);
    k_bfill  <<<FB, 256, 0, stream>>>(ei, bcur, col1, E, chunk, NB);
    k_bsort  <<<NB, 256, 0, stream>>>(col1, bstart, col, rowptr, dinv, x, xsb, N);
    k_l12g   <<<(N + 63) / 64, 512, 0, stream>>>(rowptr, col, xsb, dinv,
                                                 W1, b1, W2bf, ht1b, N);
    k_gat128pool<<<(N + 3) / 4, 256, 0, stream>>>(rowptr, col, ht1b, dinv, b2, batch, gsum, N);
    k_head   <<<G, 128, 0, stream>>>(gsum, gptr, Wlab, blab, Wd1, bd1, Wd2, bd2, out, G);
}

// Round 12
// 238.306 us; speedup vs baseline: 1.4224x; 1.1291x over previous
//
#include <hip/hip_runtime.h>
#include <math.h>

// GCN forward, CSR-gather; bf16 xs/W2/ht1; block-aggregated pooling.
// CSR build = two-level bucket sort (append-order writes only).
// Requires N <= 65536 (src packed in 16 bits) -- holds for N=50000.
// Round-12: fixes round-11's W2s staging bug (rows are 16 uint4 segments,
// not 8 -- half of W2 was unstaged garbage -> NaN). MFMA phase-2 otherwise
// unchanged: h1 -> LDS bf16 A-layout [node][f1] stride 136; W2bf
// pre-transposed [f2][f1]; v_mfma_f32_16x16x32_bf16, 16 MFMAs/wave.
// Pipeline (8 dispatches):
//   memset    : bcnt = 0
//   k_bhist   : LDS hist -> 196 global atomics; tails: gsum=0, gptr,
//               W2bf = bf16(W2^T)
//   k_scan196 : 1 block: exclusive scan -> bstart/bcur; rowptr[N]=E
//   k_bfill   : per-block LDS hist + reservation; append (dstLocal<<16|src)
//   k_bsort   : block/bucket LDS 256-bin sort -> rowptr, dinv, sorted col;
//               + xsb = bf16(x*dinv) for its own 256 nodes
//   k_l12g    : gather rank-16 -> arow; h1=relu(dinv*(arow@W1)+b1) -> LDS bf16;
//               ht1b = bf16(MFMA(h1, W2) * dinv)
//   k_gat128pool : wave/node gather, 4-node LDS merge -> ~1 atomic set/block
//   k_head    : pooled = gsum/cnt; label/domain heads

#define BCAP 24576   // max edges per 256-node bucket (mean ~8.2K; 3x headroom)

typedef __attribute__((ext_vector_type(8))) short short8;   // 8 bf16 (4 VGPRs)
typedef __attribute__((ext_vector_type(4))) float f32x4;    // MFMA accumulator

__device__ __forceinline__ void bf4acc(uint2 u, float* a) {
    a[0] += __uint_as_float(u.x << 16);
    a[1] += __uint_as_float(u.x & 0xffff0000u);
    a[2] += __uint_as_float(u.y << 16);
    a[3] += __uint_as_float(u.y & 0xffff0000u);
}

__device__ __forceinline__ unsigned short bf1(float a) {    // RNE bf16
    unsigned ua = __float_as_uint(a);
    return (unsigned short)((ua + 0x7fffu + ((ua >> 16) & 1u)) >> 16);
}

// ---- phase 1: bucket histogram (global atomics, L2-resident) + prep tails ----
__global__ __launch_bounds__(256) void k_bhist(
        const int* __restrict__ ei, int* __restrict__ bcnt,
        const int* __restrict__ batch, int* __restrict__ gptr,
        float* __restrict__ gsum, const float* __restrict__ W2,
        unsigned short* __restrict__ W2bf,
        int E, int chunk, int NB, int N, int G) {
    __shared__ int bins[256];
    for (int t = threadIdx.x; t < NB; t += 256) bins[t] = 0;
    __syncthreads();
    const int e0 = blockIdx.x * chunk;
    int e1 = e0 + chunk; if (e1 > E) e1 = E;
    for (int j = e0 + (int)threadIdx.x; j < e1; j += 256)
        atomicAdd(&bins[ei[E + j] >> 8], 1);
    __syncthreads();
    for (int t = threadIdx.x; t < NB; t += 256)
        if (bins[t]) atomicAdd(&bcnt[t], bins[t]);

    // distributed prep tails
    const int gid = blockIdx.x * 256 + threadIdx.x;
    const int gsz = gridDim.x * 256;
    for (int i = gid; i < G * 32; i += gsz)        // gsum = 0 (float4)
        ((float4*)gsum)[i] = make_float4(0.f, 0.f, 0.f, 0.f);
    for (int i = gid; i < 16384; i += gsz) {       // W2bf[f2][f1] = bf16(W2[f1][f2])
        const int f2 = i >> 7, f1 = i & 127;
        W2bf[i] = bf1(W2[f1 * 128 + f2]);
    }
    for (int g = gid; g <= G; g += gsz) {          // gptr = lower_bound(batch,g)
        int lo = 0, hi = N;
        while (lo < hi) {
            int mid = (lo + hi) >> 1;
            if (batch[mid] < g) lo = mid + 1; else hi = mid;
        }
        gptr[g] = lo;
    }
}

// ---- phase 2: scan NB bucket counts (NB <= 256), 1 block ----
__global__ void k_scan196(const int* __restrict__ bcnt, int* __restrict__ bstart,
                          int* __restrict__ bcur, int* __restrict__ rowptr,
                          int NB, int E, int N) {
    __shared__ int s[256];
    int t = threadIdx.x;
    int v = (t < NB) ? bcnt[t] : 0;
    s[t] = v;
    __syncthreads();
    for (int off = 1; off < 256; off <<= 1) {
        int add = (t >= off) ? s[t - off] : 0;
        __syncthreads();
        s[t] += add;
        __syncthreads();
    }
    if (t < NB) { bstart[t] = s[t] - v; bcur[t] = s[t] - v; }
    if (t == 0) { bstart[NB] = E; rowptr[N] = E; }
}

// ---- phase 3: bucketed append of packed (dstLocal<<16|src) ----
__global__ __launch_bounds__(256) void k_bfill(const int* __restrict__ ei,
                                               int* __restrict__ bcur,
                                               unsigned* __restrict__ col1,
                                               int E, int chunk, int NB) {
    __shared__ int bins[256];
    __shared__ int base[256];
    for (int t = threadIdx.x; t < NB; t += 256) bins[t] = 0;
    __syncthreads();
    const int e0 = blockIdx.x * chunk;
    int e1 = e0 + chunk; if (e1 > E) e1 = E;
    for (int j = e0 + (int)threadIdx.x; j < e1; j += 256)
        atomicAdd(&bins[ei[E + j] >> 8], 1);
    __syncthreads();
    for (int t = threadIdx.x; t < NB; t += 256) {
        base[t] = bins[t] ? atomicAdd(&bcur[t], bins[t]) : 0;
        bins[t] = 0;
    }
    __syncthreads();
    for (int j = e0 + (int)threadIdx.x; j < e1; j += 256) {
        int d = ei[E + j];
        int s = ei[j];
        int b = d >> 8;
        int pos = base[b] + atomicAdd(&bins[b], 1);
        col1[pos] = ((unsigned)(d & 255) << 16) | (unsigned)s;
    }
}

// ---- phase 4: per-bucket LDS sort -> exact CSR + dinv + xsb ----
__global__ __launch_bounds__(256) void k_bsort(const unsigned* __restrict__ col1,
                                               const int* __restrict__ bstart,
                                               int* __restrict__ col,
                                               int* __restrict__ rowptr,
                                               float* __restrict__ dinv,
                                               const float* __restrict__ x,
                                               unsigned short* __restrict__ xsb,
                                               int N) {
    __shared__ unsigned ec[BCAP];
    __shared__ int bins[256], sc[256];
    __shared__ float dvb[256];
    const int b = blockIdx.x, t = threadIdx.x;
    const int s0 = bstart[b];
    int cnt = bstart[b + 1] - s0;
    if (cnt > BCAP) cnt = BCAP;        // safety clamp (never hit for this E,N)
    for (int i = t; i < cnt; i += 256) ec[i] = col1[s0 + i];
    bins[t] = 0;
    __syncthreads();
    for (int i = t; i < cnt; i += 256) atomicAdd(&bins[ec[i] >> 16], 1);
    __syncthreads();
    const int v = bins[t];
    sc[t] = v;
    __syncthreads();
    for (int off = 1; off < 256; off <<= 1) {
        int add = (t >= off) ? sc[t - off] : 0;
        __syncthreads();
        sc[t] += add;
        __syncthreads();
    }
    const int ex = sc[t] - v;
    __syncthreads();
    sc[t] = ex;          // exclusive local offsets
    bins[t] = 0;         // reuse as per-node cursor
    const float dv = rsqrtf((float)(v + 1));
    dvb[t] = dv;
    const int n0 = b * 256;
    if (n0 + t < N) {
        rowptr[n0 + t] = s0 + ex;
        dinv[n0 + t] = dv;
    }
    __syncthreads();
    for (int i = t; i < cnt; i += 256) {
        unsigned e = ec[i];
        int dl = e >> 16;
        int p = sc[dl] + atomicAdd(&bins[dl], 1);
        col[s0 + p] = (int)(e & 0xffffu);
    }
    // xsb = bf16(x * dinv) for this bucket's nodes (coalesced)
    int nn = N - n0; if (nn > 256) nn = 256;
    const int lim = nn * 16;
    for (int i = t; i < lim; i += 256) {
        float vx = x[(size_t)n0 * 16 + i] * dvb[i >> 4];
        xsb[(size_t)n0 * 16 + i] = bf1(vx);
    }
}

// ---- FUSED gat16 + l12 (MFMA): 64 nodes/block, 512 threads (8 waves),
//      ~57 KB LDS -> 2 blocks/CU.
//      gather: 8 lanes/node x 8 concurrent nodes/wave -> arow f32 LDS
//      phase1: h1 = relu(dinv*(arow@W1)+b1) -> h1b bf16 [node][f1] stride 136
//      phase2: D = h1 @ W2 via mfma_f32_16x16x32_bf16; wave = (mt = w&3,
//              nh = w>>2); A[m=lane&15][k=quad*8+j], B from W2s[f2][f1]
//              (pre-transposed), C/D col=lane&15 row=quad*4+reg.
__global__ __launch_bounds__(512, 4) void k_l12g(
        const int* __restrict__ rowptr, const int* __restrict__ col,
        const unsigned short* __restrict__ xsb,
        const float* __restrict__ dinv,
        const float* __restrict__ W1, const float* __restrict__ b1,
        const unsigned short* __restrict__ W2bf,   // [f2][f1] bf16
        unsigned short* __restrict__ ht1b, int N) {
    __shared__ __align__(16) unsigned short W2s[128 * 136];  // [f2][f1] padded
    __shared__ __align__(16) unsigned short h1b[64 * 136];   // [node][f1] padded
    __shared__ __align__(16) float arow[64 * 16];
    __shared__ float dv[64];
    const int tid = threadIdx.x;
    const int n0 = blockIdx.x * 64;
    const int w = tid >> 6, lane = tid & 63;

    // stage W2^T (bf16) into padded LDS rows: 128 rows x 16 uint4 segments
    // (round-11 bug: used 8 segments/row -> half of W2 was garbage)
    for (int i = tid; i < 2048; i += 512) {
        const int f2 = i >> 4, seg = i & 15;
        *(uint4*)&W2s[f2 * 136 + seg * 8] = ((const uint4*)W2bf)[i];
    }
    if (tid < 64) dv[tid] = (n0 + tid < N) ? dinv[n0 + tid] : 0.f;

    // gather: 8 lanes per node (2 edge slots x 4 quarters), 8 nodes per wave
    {
        const int nd = lane >> 3, sub = lane & 7;
        const int slot = sub >> 2, qq = sub & 3;
        const int j = w * 8 + nd;
        const int n = n0 + j;
        float a[4] = {0.f, 0.f, 0.f, 0.f};
        if (n < N) {
            const int r1 = rowptr[n + 1];
            for (int e = rowptr[n] + slot; e < r1; e += 2)
                bf4acc(*(const uint2*)(xsb + (size_t)col[e] * 16 + qq * 4), a);
        }
#pragma unroll
        for (int i = 0; i < 4; ++i) a[i] += __shfl_xor(a[i], 4);
        if (slot == 0) {
            if (n < N) {   // self loop
                bf4acc(*(const uint2*)(xsb + (size_t)n * 16 + qq * 4), a);
                *(float4*)&arow[j * 16 + qq * 4] = make_float4(a[0], a[1], a[2], a[3]);
            } else {
                *(float4*)&arow[j * 16 + qq * 4] = make_float4(0.f, 0.f, 0.f, 0.f);
            }
        }
    }
    const int f = tid & 127, jg = tid >> 7;
    float w1r[16];
#pragma unroll
    for (int k = 0; k < 16; ++k) w1r[k] = W1[k * 128 + f];
    const float bias = b1[f];
    __syncthreads();

    // phase 1: h1 (bf16) into A-layout LDS
#pragma unroll 4
    for (int j = jg * 16; j < jg * 16 + 16; ++j) {
        float s = 0.f;
#pragma unroll
        for (int k = 0; k < 16; ++k) s += arow[j * 16 + k] * w1r[k];
        h1b[j * 136 + f] = bf1(fmaxf(dv[j] * s + bias, 0.f));
    }
    __syncthreads();

    // phase 2: MFMA, D[64x128] = h1[64x128] @ W2[128x128]
    const int mt = w & 3, nh = w >> 2;
    const int lm = lane & 15, quad = lane >> 4;
    f32x4 acc[4];
#pragma unroll
    for (int t = 0; t < 4; ++t) acc[t] = (f32x4){0.f, 0.f, 0.f, 0.f};
#pragma unroll
    for (int kb = 0; kb < 4; ++kb) {
        const short8 af = *(const short8*)&h1b[(mt * 16 + lm) * 136 + kb * 32 + quad * 8];
#pragma unroll
        for (int t = 0; t < 4; ++t) {
            const short8 bfv = *(const short8*)&W2s[(nh * 64 + t * 16 + lm) * 136 + kb * 32 + quad * 8];
            acc[t] = __builtin_amdgcn_mfma_f32_16x16x32_bf16(af, bfv, acc[t], 0, 0, 0);
        }
    }
    // epilogue: *dinv, pack bf16, store
#pragma unroll
    for (int t = 0; t < 4; ++t) {
        const int f2 = nh * 64 + t * 16 + lm;
#pragma unroll
        for (int r = 0; r < 4; ++r) {
            const int j = mt * 16 + quad * 4 + r;
            const int n = n0 + j;
            if (n < N)
                ht1b[(size_t)n * 128 + f2] = bf1(acc[t][r] * dv[j]);
        }
    }
}

// Wave/node gather (2 halves x 32 lanes x uint2, 4x unroll -> 8 rows in flight),
// then 4-node LDS merge -> ~1 atomic set per block (batch sorted).
__global__ __launch_bounds__(256) void k_gat128pool(
        const int* __restrict__ rowptr, const int* __restrict__ col,
        const unsigned short* __restrict__ ht1b,
        const float* __restrict__ dinv, const float* __restrict__ b2,
        const int* __restrict__ batch, float* __restrict__ gsum, int N) {
    __shared__ __align__(16) float h2s[4][128];
    __shared__ int bats[4];
    const int wave = threadIdx.x >> 6, lane = threadIdx.x & 63;
    const int half = lane >> 5, q = lane & 31;
    const int n = blockIdx.x * 4 + wave;
    float a[4] = {0.f, 0.f, 0.f, 0.f};
    if (n < N) {
        const int r0 = rowptr[n], r1 = rowptr[n + 1];
        int j = r0 + half;
        while (j + 6 < r1) {
            int s0 = col[j], s1 = col[j + 2], s2 = col[j + 4], s3 = col[j + 6];
            uint2 u0 = *(const uint2*)(ht1b + (size_t)s0 * 128 + q * 4);
            uint2 u1 = *(const uint2*)(ht1b + (size_t)s1 * 128 + q * 4);
            uint2 u2 = *(const uint2*)(ht1b + (size_t)s2 * 128 + q * 4);
            uint2 u3 = *(const uint2*)(ht1b + (size_t)s3 * 128 + q * 4);
            bf4acc(u0, a); bf4acc(u1, a); bf4acc(u2, a); bf4acc(u3, a);
            j += 8;
        }
        while (j < r1) {
            bf4acc(*(const uint2*)(ht1b + (size_t)col[j] * 128 + q * 4), a);
            j += 2;
        }
        if (half == 0)  // self loop
            bf4acc(*(const uint2*)(ht1b + (size_t)n * 128 + q * 4), a);
    }
#pragma unroll
    for (int i = 0; i < 4; ++i) a[i] += __shfl_xor(a[i], 32);
    if (half == 0) {
        if (n < N) {
            const float d = dinv[n];
            const float4 bb = *(const float4*)(b2 + q * 4);
            h2s[wave][q * 4 + 0] = fmaxf(a[0] * d + bb.x, 0.f);
            h2s[wave][q * 4 + 1] = fmaxf(a[1] * d + bb.y, 0.f);
            h2s[wave][q * 4 + 2] = fmaxf(a[2] * d + bb.z, 0.f);
            h2s[wave][q * 4 + 3] = fmaxf(a[3] * d + bb.w, 0.f);
            if (q == 0) bats[wave] = batch[n];
        } else {
            h2s[wave][q * 4 + 0] = 0.f; h2s[wave][q * 4 + 1] = 0.f;
            h2s[wave][q * 4 + 2] = 0.f; h2s[wave][q * 4 + 3] = 0.f;
            if (q == 0) bats[wave] = -1;
        }
    }
    __syncthreads();
    if (threadIdx.x < 32) {
        const int qq = threadIdx.x;
        const int b0 = bats[0], b1 = bats[1], b2i = bats[2], b3 = bats[3];
        float4 r0v = *(const float4*)&h2s[0][qq * 4];
        float4 r1v = *(const float4*)&h2s[1][qq * 4];
        float4 r2v = *(const float4*)&h2s[2][qq * 4];
        float4 r3v = *(const float4*)&h2s[3][qq * 4];
        bool m1 = false, m2 = false, m3 = false;
        if (b0 >= 0) {
            float4 s = r0v;
            if (b1 == b0) { s.x += r1v.x; s.y += r1v.y; s.z += r1v.z; s.w += r1v.w; m1 = true; }
            if (b2i == b0) { s.x += r2v.x; s.y += r2v.y; s.z += r2v.z; s.w += r2v.w; m2 = true; }
            if (b3 == b0) { s.x += r3v.x; s.y += r3v.y; s.z += r3v.z; s.w += r3v.w; m3 = true; }
            float* gs = gsum + (size_t)b0 * 128 + qq * 4;
            unsafeAtomicAdd(gs + 0, s.x); unsafeAtomicAdd(gs + 1, s.y);
            unsafeAtomicAdd(gs + 2, s.z); unsafeAtomicAdd(gs + 3, s.w);
        }
        if (!m1 && b1 >= 0) {
            float4 s = r1v;
            if (b2i == b1) { s.x += r2v.x; s.y += r2v.y; s.z += r2v.z; s.w += r2v.w; m2 = true; }
            if (b3 == b1) { s.x += r3v.x; s.y += r3v.y; s.z += r3v.z; s.w += r3v.w; m3 = true; }
            float* gs = gsum + (size_t)b1 * 128 + qq * 4;
            unsafeAtomicAdd(gs + 0, s.x); unsafeAtomicAdd(gs + 1, s.y);
            unsafeAtomicAdd(gs + 2, s.z); unsafeAtomicAdd(gs + 3, s.w);
        }
        if (!m2 && b2i >= 0) {
            float4 s = r2v;
            if (b3 == b2i) { s.x += r3v.x; s.y += r3v.y; s.z += r3v.z; s.w += r3v.w; m3 = true; }
            float* gs = gsum + (size_t)b2i * 128 + qq * 4;
            unsafeAtomicAdd(gs + 0, s.x); unsafeAtomicAdd(gs + 1, s.y);
            unsafeAtomicAdd(gs + 2, s.z); unsafeAtomicAdd(gs + 3, s.w);
        }
        if (!m3 && b3 >= 0) {
            float* gs = gsum + (size_t)b3 * 128 + qq * 4;
            unsafeAtomicAdd(gs + 0, r3v.x); unsafeAtomicAdd(gs + 1, r3v.y);
            unsafeAtomicAdd(gs + 2, r3v.z); unsafeAtomicAdd(gs + 3, r3v.w);
        }
    }
}

__global__ __launch_bounds__(128) void k_head(
        const float* __restrict__ gsum, const int* __restrict__ gptr,
        const float* __restrict__ Wlab, const float* __restrict__ blab,
        const float* __restrict__ Wd1, const float* __restrict__ bd1,
        const float* __restrict__ Wd2, const float* __restrict__ bd2,
        float* __restrict__ out, int G) {
    __shared__ float sp[128];
    __shared__ float red[128];
    __shared__ float hd[64];
    const int g = blockIdx.x, t = threadIdx.x;
    const float cnt = (float)(gptr[g + 1] - gptr[g]);
    const float invc = 1.f / fmaxf(cnt, 1.f);
    const float pooled = gsum[g * 128 + t] * invc;
    sp[t] = pooled;
    red[t] = pooled * Wlab[t];
    __syncthreads();
    for (int off = 64; off > 0; off >>= 1) {
        if (t < off) red[t] += red[t + off];
        __syncthreads();
    }
    if (t == 0) {
        float z = red[0] + blab[0];
        out[g] = 1.f / (1.f + expf(-z));
    }
    if (t < 64) {
        float s = bd1[t];
        for (int f = 0; f < 128; ++f) s += sp[f] * Wd1[f * 64 + t];
        hd[t] = fmaxf(s, 0.f);
    }
    __syncthreads();
    if (t < 2) {
        float s = bd2[t];
        for (int j = 0; j < 64; ++j) s += hd[j] * Wd2[j * 2 + t];
        out[G + g * 2 + t] = s;
    }
}

extern "C" void kernel_launch(void* const* d_in, const int* in_sizes, int n_in,
                              void* d_out, int out_size, void* d_ws, size_t ws_size,
                              hipStream_t stream) {
    const float* x     = (const float*)d_in[0];
    const int*   ei    = (const int*)d_in[1];   // [2,E]: ei[e]=src, ei[E+e]=dst
    const int*   batch = (const int*)d_in[2];
    const float* W1    = (const float*)d_in[3];
    const float* b1    = (const float*)d_in[4];
    const float* W2    = (const float*)d_in[5];
    const float* b2    = (const float*)d_in[6];
    const float* Wlab  = (const float*)d_in[7];
    const float* blab  = (const float*)d_in[8];
    const float* Wd1   = (const float*)d_in[9];
    const float* bd1   = (const float*)d_in[10];
    const float* Wd2   = (const float*)d_in[11];
    const float* bd2   = (const float*)d_in[12];
    float* out = (float*)d_out;

    const int N = in_sizes[0] / 16;
    const int E = in_sizes[1] / 2;
    const int G = out_size / 3;
    const int NB = (N + 255) >> 8;             // node buckets of 256

    char* p = (char*)d_ws;
    auto carve = [&](size_t bytes) {
        void* r = (void*)p;
        p += (bytes + 255) & ~(size_t)255;
        return r;
    };
    int*      bcnt   = (int*)     carve(256 * 4);
    int*      bstart = (int*)     carve((size_t)(NB + 1) * 4);
    int*      bcur   = (int*)     carve((size_t)NB * 4);
    unsigned* col1   = (unsigned*)carve((size_t)E * 4);
    int*      col    = (int*)     carve((size_t)E * 4);
    int*      rowptr = (int*)     carve((size_t)(N + 1) * 4);
    int*      gptr   = (int*)     carve((size_t)(G + 1) * 4);
    float*    dinv   = (float*)   carve((size_t)N * 4);
    unsigned short* xsb  = (unsigned short*)carve((size_t)N * 16 * 2);
    unsigned short* W2bf = (unsigned short*)carve(128 * 128 * 2);
    unsigned short* ht1b = (unsigned short*)carve((size_t)N * 128 * 2);
    float*    gsum   = (float*)   carve((size_t)G * 128 * 4);

    const int FB = 256;                        // blocks for bhist/bfill
    const int chunk = (E + FB - 1) / FB;

    hipMemsetAsync(bcnt, 0, 256 * 4, stream);
    k_bhist  <<<FB, 256, 0, stream>>>(ei, bcnt, batch, gptr, gsum, W2, W2bf,
                                      E, chunk, NB, N, G);
    k_scan196<<<1, 256, 0, stream>>>(bcnt, bstart, bcur, rowptr, NB, E, N);
    k_bfill  <<<FB, 256, 0, stream>>>(ei, bcur, col1, E, chunk, NB);
    k_bsort  <<<NB, 256, 0, stream>>>(col1, bstart, col, rowptr, dinv, x, xsb, N);
    k_l12g   <<<(N + 63) / 64, 512, 0, stream>>>(rowptr, col, xsb, dinv,
                                                 W1, b1, W2bf, ht1b, N);
    k_gat128pool<<<(N + 3) / 4, 256, 0, stream>>>(rowptr, col, ht1b, dinv, b2, batch, gsum, N);
    k_head   <<<G, 128, 0, stream>>>(gsum, gptr, Wlab, blab, Wd1, bd1, Wd2, bd2, out, G);
}

// Round 13
// 229.290 us; speedup vs baseline: 1.4784x; 1.0393x over previous
//
#include <hip/hip_runtime.h>
#include <math.h>

// GCN forward, CSR-gather; bf16 xs/W2/ht1; MFMA layer-2 dense; block-
// aggregated pooling. CSR build = single-pass fixed-capacity bucket sort:
// col1 is 196 buckets x BCAP stride, k_bfill reserves per-(block,bucket)
// runs with one atomic each (append-order writes only -- rounds 5-8 showed
// exact-position scatter costs 60-100MB HBM writeback), k_bsort self-scans
// the bucket counts (196 ints, L2-hot) so no separate hist/scan kernels.
// Requires N <= 65536 (src packed in 16 bits) -- holds for N=50000.
// Pipeline (6 dispatches):
//   memset    : bcnt = 0 (784 B)
//   k_bfill   : per-block LDS hist + reservation -> col1[b*BCAP + pos] =
//               (dstLocal<<16|src); tails: gsum=0, gptr, W2bf=bf16(W2^T)
//   k_bsort   : block/bucket: LDS scan of bcnt -> s0; LDS 256-bin sort ->
//               rowptr, dinv, sorted col; xsb = bf16(x*dinv) for its nodes
//   k_l12g    : gather rank-16 -> arow; h1=relu(dinv*(arow@W1)+b1) -> LDS
//               bf16; ht1b = bf16(MFMA(h1,W2)*dinv)  [16x16x32 bf16 MFMA]
//   k_gat128pool : wave/node gather, 8-node LDS run-merge -> ~1 atomic
//                  set per block (batch sorted)
//   k_head    : pooled = gsum/cnt; label/domain heads

#define BCAP 12288   // bucket capacity (mean fill ~8.2K, 45 sigma headroom)

typedef __attribute__((ext_vector_type(8))) short short8;   // 8 bf16 (4 VGPRs)
typedef __attribute__((ext_vector_type(4))) float f32x4;    // MFMA accumulator

__device__ __forceinline__ void bf4acc(uint2 u, float* a) {
    a[0] += __uint_as_float(u.x << 16);
    a[1] += __uint_as_float(u.x & 0xffff0000u);
    a[2] += __uint_as_float(u.y << 16);
    a[3] += __uint_as_float(u.y & 0xffff0000u);
}

__device__ __forceinline__ unsigned short bf1(float a) {    // RNE bf16
    unsigned ua = __float_as_uint(a);
    return (unsigned short)((ua + 0x7fffu + ((ua >> 16) & 1u)) >> 16);
}

// ---- single-pass bucketed fill + prep tails ----
__global__ __launch_bounds__(256) void k_bfill(
        const int* __restrict__ ei, int* __restrict__ bcnt,
        unsigned* __restrict__ col1,
        const int* __restrict__ batch, int* __restrict__ gptr,
        float* __restrict__ gsum, const float* __restrict__ W2,
        unsigned short* __restrict__ W2bf,
        int E, int chunk, int NB, int N, int G) {
    __shared__ int bins[256];
    __shared__ int base[256];
    for (int t = threadIdx.x; t < NB; t += 256) bins[t] = 0;
    __syncthreads();
    const int e0 = blockIdx.x * chunk;
    int e1 = e0 + chunk; if (e1 > E) e1 = E;
    for (int j = e0 + (int)threadIdx.x; j < e1; j += 256)
        atomicAdd(&bins[ei[E + j] >> 8], 1);
    __syncthreads();
    for (int t = threadIdx.x; t < NB; t += 256) {
        base[t] = bins[t] ? atomicAdd(&bcnt[t], bins[t]) : 0;
        bins[t] = 0;
    }
    __syncthreads();
    for (int j = e0 + (int)threadIdx.x; j < e1; j += 256) {
        int d = ei[E + j];              // L2-warm (read in hist pass)
        int s = ei[j];
        int b = d >> 8;
        int pos = base[b] + atomicAdd(&bins[b], 1);
        if (pos < BCAP)
            col1[(size_t)b * BCAP + pos] = ((unsigned)(d & 255) << 16) | (unsigned)s;
    }

    // distributed prep tails
    const int gid = blockIdx.x * 256 + threadIdx.x;
    const int gsz = gridDim.x * 256;
    for (int i = gid; i < G * 32; i += gsz)        // gsum = 0 (float4)
        ((float4*)gsum)[i] = make_float4(0.f, 0.f, 0.f, 0.f);
    for (int i = gid; i < 16384; i += gsz) {       // W2bf[f2][f1] = bf16(W2[f1][f2])
        const int f2 = i >> 7, f1 = i & 127;
        W2bf[i] = bf1(W2[f1 * 128 + f2]);
    }
    for (int g = gid; g <= G; g += gsz) {          // gptr = lower_bound(batch,g)
        int lo = 0, hi = N;
        while (lo < hi) {
            int mid = (lo + hi) >> 1;
            if (batch[mid] < g) lo = mid + 1; else hi = mid;
        }
        gptr[g] = lo;
    }
}

// ---- per-bucket LDS sort -> exact CSR + dinv + xsb (self-scans bcnt) ----
__global__ __launch_bounds__(256) void k_bsort(const unsigned* __restrict__ col1,
                                               const int* __restrict__ bcnt,
                                               int* __restrict__ col,
                                               int* __restrict__ rowptr,
                                               float* __restrict__ dinv,
                                               const float* __restrict__ x,
                                               unsigned short* __restrict__ xsb,
                                               int N, int E, int NB) {
    __shared__ unsigned ec[BCAP];
    __shared__ int bins[256], sc[256];
    __shared__ float dvb[256];
    const int b = blockIdx.x, t = threadIdx.x;

    // bucket-offset scan (196 ints, L2-hot): s0 = sum_{i<b} bcnt[i]
    {
        int v = (t < NB) ? bcnt[t] : 0;
        bins[t] = v;
        __syncthreads();
        for (int off = 1; off < 256; off <<= 1) {
            int add = (t >= off) ? bins[t - off] : 0;
            __syncthreads();
            bins[t] += add;
            __syncthreads();
        }
    }
    const int s0 = (b == 0) ? 0 : bins[b - 1];
    int cnt = bcnt[b];
    if (cnt > BCAP) cnt = BCAP;        // safety clamp (never hit for this E,N)
    __syncthreads();

    for (int i = t; i < cnt; i += 256) ec[i] = col1[(size_t)b * BCAP + i];
    bins[t] = 0;
    __syncthreads();
    for (int i = t; i < cnt; i += 256) atomicAdd(&bins[ec[i] >> 16], 1);
    __syncthreads();
    const int v = bins[t];
    sc[t] = v;
    __syncthreads();
    for (int off = 1; off < 256; off <<= 1) {
        int add = (t >= off) ? sc[t - off] : 0;
        __syncthreads();
        sc[t] += add;
        __syncthreads();
    }
    const int ex = sc[t] - v;
    __syncthreads();
    sc[t] = ex;          // exclusive local offsets
    bins[t] = 0;         // reuse as per-node cursor
    const float dv = rsqrtf((float)(v + 1));
    dvb[t] = dv;
    const int n0 = b * 256;
    if (n0 + t < N) {
        rowptr[n0 + t] = s0 + ex;
        dinv[n0 + t] = dv;
    }
    if (b == 0 && t == 0) rowptr[N] = E;
    __syncthreads();
    for (int i = t; i < cnt; i += 256) {
        unsigned e = ec[i];
        int dl = e >> 16;
        int p = sc[dl] + atomicAdd(&bins[dl], 1);
        col[s0 + p] = (int)(e & 0xffffu);
    }
    // xsb = bf16(x * dinv) for this bucket's nodes (coalesced)
    int nn = N - n0; if (nn > 256) nn = 256;
    const int lim = nn * 16;
    for (int i = t; i < lim; i += 256) {
        float vx = x[(size_t)n0 * 16 + i] * dvb[i >> 4];
        xsb[(size_t)n0 * 16 + i] = bf1(vx);
    }
}

// ---- FUSED gat16 + l12 (MFMA): 64 nodes/block, 512 threads (8 waves),
//      ~57 KB LDS -> 2 blocks/CU.
__global__ __launch_bounds__(512, 4) void k_l12g(
        const int* __restrict__ rowptr, const int* __restrict__ col,
        const unsigned short* __restrict__ xsb,
        const float* __restrict__ dinv,
        const float* __restrict__ W1, const float* __restrict__ b1,
        const unsigned short* __restrict__ W2bf,   // [f2][f1] bf16
        unsigned short* __restrict__ ht1b, int N) {
    __shared__ __align__(16) unsigned short W2s[128 * 136];  // [f2][f1] padded
    __shared__ __align__(16) unsigned short h1b[64 * 136];   // [node][f1] padded
    __shared__ __align__(16) float arow[64 * 16];
    __shared__ float dv[64];
    const int tid = threadIdx.x;
    const int n0 = blockIdx.x * 64;
    const int w = tid >> 6, lane = tid & 63;

    // stage W2^T (bf16): 128 rows x 16 uint4 segments
    for (int i = tid; i < 2048; i += 512) {
        const int f2 = i >> 4, seg = i & 15;
        *(uint4*)&W2s[f2 * 136 + seg * 8] = ((const uint4*)W2bf)[i];
    }
    if (tid < 64) dv[tid] = (n0 + tid < N) ? dinv[n0 + tid] : 0.f;

    // gather: 8 lanes per node (2 edge slots x 4 quarters), 8 nodes per wave
    {
        const int nd = lane >> 3, sub = lane & 7;
        const int slot = sub >> 2, qq = sub & 3;
        const int j = w * 8 + nd;
        const int n = n0 + j;
        float a[4] = {0.f, 0.f, 0.f, 0.f};
        if (n < N) {
            const int r1 = rowptr[n + 1];
            for (int e = rowptr[n] + slot; e < r1; e += 2)
                bf4acc(*(const uint2*)(xsb + (size_t)col[e] * 16 + qq * 4), a);
        }
#pragma unroll
        for (int i = 0; i < 4; ++i) a[i] += __shfl_xor(a[i], 4);
        if (slot == 0) {
            if (n < N) {   // self loop
                bf4acc(*(const uint2*)(xsb + (size_t)n * 16 + qq * 4), a);
                *(float4*)&arow[j * 16 + qq * 4] = make_float4(a[0], a[1], a[2], a[3]);
            } else {
                *(float4*)&arow[j * 16 + qq * 4] = make_float4(0.f, 0.f, 0.f, 0.f);
            }
        }
    }
    const int f = tid & 127, jg = tid >> 7;
    float w1r[16];
#pragma unroll
    for (int k = 0; k < 16; ++k) w1r[k] = W1[k * 128 + f];
    const float bias = b1[f];
    __syncthreads();

    // phase 1: h1 (bf16) into A-layout LDS
#pragma unroll 4
    for (int j = jg * 16; j < jg * 16 + 16; ++j) {
        float s = 0.f;
#pragma unroll
        for (int k = 0; k < 16; ++k) s += arow[j * 16 + k] * w1r[k];
        h1b[j * 136 + f] = bf1(fmaxf(dv[j] * s + bias, 0.f));
    }
    __syncthreads();

    // phase 2: MFMA, D[64x128] = h1[64x128] @ W2[128x128]
    const int mt = w & 3, nh = w >> 2;
    const int lm = lane & 15, quad = lane >> 4;
    f32x4 acc[4];
#pragma unroll
    for (int t = 0; t < 4; ++t) acc[t] = (f32x4){0.f, 0.f, 0.f, 0.f};
#pragma unroll
    for (int kb = 0; kb < 4; ++kb) {
        const short8 af = *(const short8*)&h1b[(mt * 16 + lm) * 136 + kb * 32 + quad * 8];
#pragma unroll
        for (int t = 0; t < 4; ++t) {
            const short8 bfv = *(const short8*)&W2s[(nh * 64 + t * 16 + lm) * 136 + kb * 32 + quad * 8];
            acc[t] = __builtin_amdgcn_mfma_f32_16x16x32_bf16(af, bfv, acc[t], 0, 0, 0);
        }
    }
    // epilogue: *dinv, pack bf16, store
#pragma unroll
    for (int t = 0; t < 4; ++t) {
        const int f2 = nh * 64 + t * 16 + lm;
#pragma unroll
        for (int r = 0; r < 4; ++r) {
            const int j = mt * 16 + quad * 4 + r;
            const int n = n0 + j;
            if (n < N)
                ht1b[(size_t)n * 128 + f2] = bf1(acc[t][r] * dv[j]);
        }
    }
}

// Wave/node gather (2 halves x 32 lanes x uint2, 4x unroll -> 8 rows in
// flight), then 8-node LDS run-merge (batch sorted) -> ~1 atomic set/block.
__global__ __launch_bounds__(512) void k_gat128pool(
        const int* __restrict__ rowptr, const int* __restrict__ col,
        const unsigned short* __restrict__ ht1b,
        const float* __restrict__ dinv, const float* __restrict__ b2,
        const int* __restrict__ batch, float* __restrict__ gsum, int N) {
    __shared__ __align__(16) float h2s[8][128];
    __shared__ int bats[8];
    const int wave = threadIdx.x >> 6, lane = threadIdx.x & 63;
    const int half = lane >> 5, q = lane & 31;
    const int n = blockIdx.x * 8 + wave;
    float a[4] = {0.f, 0.f, 0.f, 0.f};
    if (n < N) {
        const int r0 = rowptr[n], r1 = rowptr[n + 1];
        int j = r0 + half;
        while (j + 6 < r1) {
            int s0 = col[j], s1 = col[j + 2], s2 = col[j + 4], s3 = col[j + 6];
            uint2 u0 = *(const uint2*)(ht1b + (size_t)s0 * 128 + q * 4);
            uint2 u1 = *(const uint2*)(ht1b + (size_t)s1 * 128 + q * 4);
            uint2 u2 = *(const uint2*)(ht1b + (size_t)s2 * 128 + q * 4);
            uint2 u3 = *(const uint2*)(ht1b + (size_t)s3 * 128 + q * 4);
            bf4acc(u0, a); bf4acc(u1, a); bf4acc(u2, a); bf4acc(u3, a);
            j += 8;
        }
        while (j < r1) {
            bf4acc(*(const uint2*)(ht1b + (size_t)col[j] * 128 + q * 4), a);
            j += 2;
        }
        if (half == 0)  // self loop
            bf4acc(*(const uint2*)(ht1b + (size_t)n * 128 + q * 4), a);
    }
#pragma unroll
    for (int i = 0; i < 4; ++i) a[i] += __shfl_xor(a[i], 32);
    if (half == 0) {
        if (n < N) {
            const float d = dinv[n];
            const float4 bb = *(const float4*)(b2 + q * 4);
            h2s[wave][q * 4 + 0] = fmaxf(a[0] * d + bb.x, 0.f);
            h2s[wave][q * 4 + 1] = fmaxf(a[1] * d + bb.y, 0.f);
            h2s[wave][q * 4 + 2] = fmaxf(a[2] * d + bb.z, 0.f);
            h2s[wave][q * 4 + 3] = fmaxf(a[3] * d + bb.w, 0.f);
            if (q == 0) bats[wave] = batch[n];
        } else {
            h2s[wave][q * 4 + 0] = 0.f; h2s[wave][q * 4 + 1] = 0.f;
            h2s[wave][q * 4 + 2] = 0.f; h2s[wave][q * 4 + 3] = 0.f;
            if (q == 0) bats[wave] = -1;
        }
    }
    __syncthreads();
    if (threadIdx.x < 32) {
        const int qq = threadIdx.x;
        int bprev = bats[0];
        float4 acc4 = *(const float4*)&h2s[0][qq * 4];
#pragma unroll
        for (int wv = 1; wv < 8; ++wv) {
            const int bw = bats[wv];   // wave-uniform branch (LDS scalar)
            const float4 rv = *(const float4*)&h2s[wv][qq * 4];
            if (bw == bprev) {
                acc4.x += rv.x; acc4.y += rv.y; acc4.z += rv.z; acc4.w += rv.w;
            } else {
                if (bprev >= 0) {
                    float* gs = gsum + (size_t)bprev * 128 + qq * 4;
                    unsafeAtomicAdd(gs + 0, acc4.x); unsafeAtomicAdd(gs + 1, acc4.y);
                    unsafeAtomicAdd(gs + 2, acc4.z); unsafeAtomicAdd(gs + 3, acc4.w);
                }
                bprev = bw; acc4 = rv;
            }
        }
        if (bprev >= 0) {
            float* gs = gsum + (size_t)bprev * 128 + qq * 4;
            unsafeAtomicAdd(gs + 0, acc4.x); unsafeAtomicAdd(gs + 1, acc4.y);
            unsafeAtomicAdd(gs + 2, acc4.z); unsafeAtomicAdd(gs + 3, acc4.w);
        }
    }
}

__global__ __launch_bounds__(128) void k_head(
        const float* __restrict__ gsum, const int* __restrict__ gptr,
        const float* __restrict__ Wlab, const float* __restrict__ blab,
        const float* __restrict__ Wd1, const float* __restrict__ bd1,
        const float* __restrict__ Wd2, const float* __restrict__ bd2,
        float* __restrict__ out, int G) {
    __shared__ float sp[128];
    __shared__ float red[128];
    __shared__ float hd[64];
    const int g = blockIdx.x, t = threadIdx.x;
    const float cnt = (float)(gptr[g + 1] - gptr[g]);
    const float invc = 1.f / fmaxf(cnt, 1.f);
    const float pooled = gsum[g * 128 + t] * invc;
    sp[t] = pooled;
    red[t] = pooled * Wlab[t];
    __syncthreads();
    for (int off = 64; off > 0; off >>= 1) {
        if (t < off) red[t] += red[t + off];
        __syncthreads();
    }
    if (t == 0) {
        float z = red[0] + blab[0];
        out[g] = 1.f / (1.f + expf(-z));
    }
    if (t < 64) {
        float s = bd1[t];
        for (int f = 0; f < 128; ++f) s += sp[f] * Wd1[f * 64 + t];
        hd[t] = fmaxf(s, 0.f);
    }
    __syncthreads();
    if (t < 2) {
        float s = bd2[t];
        for (int j = 0; j < 64; ++j) s += hd[j] * Wd2[j * 2 + t];
        out[G + g * 2 + t] = s;
    }
}

extern "C" void kernel_launch(void* const* d_in, const int* in_sizes, int n_in,
                              void* d_out, int out_size, void* d_ws, size_t ws_size,
                              hipStream_t stream) {
    const float* x     = (const float*)d_in[0];
    const int*   ei    = (const int*)d_in[1];   // [2,E]: ei[e]=src, ei[E+e]=dst
    const int*   batch = (const int*)d_in[2];
    const float* W1    = (const float*)d_in[3];
    const float* b1    = (const float*)d_in[4];
    const float* W2    = (const float*)d_in[5];
    const float* b2    = (const float*)d_in[6];
    const float* Wlab  = (const float*)d_in[7];
    const float* blab  = (const float*)d_in[8];
    const float* Wd1   = (const float*)d_in[9];
    const float* bd1   = (const float*)d_in[10];
    const float* Wd2   = (const float*)d_in[11];
    const float* bd2   = (const float*)d_in[12];
    float* out = (float*)d_out;

    const int N = in_sizes[0] / 16;
    const int E = in_sizes[1] / 2;
    const int G = out_size / 3;
    const int NB = (N + 255) >> 8;             // node buckets of 256

    char* p = (char*)d_ws;
    auto carve = [&](size_t bytes) {
        void* r = (void*)p;
        p += (bytes + 255) & ~(size_t)255;
        return r;
    };
    int*      bcnt   = (int*)     carve(256 * 4);
    unsigned* col1   = (unsigned*)carve((size_t)NB * BCAP * 4);
    int*      col    = (int*)     carve((size_t)E * 4);
    int*      rowptr = (int*)     carve((size_t)(N + 1) * 4);
    int*      gptr   = (int*)     carve((size_t)(G + 1) * 4);
    float*    dinv   = (float*)   carve((size_t)N * 4);
    unsigned short* xsb  = (unsigned short*)carve((size_t)N * 16 * 2);
    unsigned short* W2bf = (unsigned short*)carve(128 * 128 * 2);
    unsigned short* ht1b = (unsigned short*)carve((size_t)N * 128 * 2);
    float*    gsum   = (float*)   carve((size_t)G * 128 * 4);

    const int FB = 256;                        // blocks for bfill
    const int chunk = (E + FB - 1) / FB;

    hipMemsetAsync(bcnt, 0, 256 * 4, stream);
    k_bfill  <<<FB, 256, 0, stream>>>(ei, bcnt, col1, batch, gptr, gsum, W2,
                                      W2bf, E, chunk, NB, N, G);
    k_bsort  <<<NB, 256, 0, stream>>>(col1, bcnt, col, rowptr, dinv, x, xsb,
                                      N, E, NB);
    k_l12g   <<<(N + 63) / 64, 512, 0, stream>>>(rowptr, col, xsb, dinv,
                                                 W1, b1, W2bf, ht1b, N);
    k_gat128pool<<<(N + 7) / 8, 512, 0, stream>>>(rowptr, col, ht1b, dinv, b2,
                                                  batch, gsum, N);
    k_head   <<<G, 128, 0, stream>>>(gsum, gptr, Wlab, blab, Wd1, bd1, Wd2,
                                     bd2, out, G);
}